// Round 6
// baseline (2586.510 us; speedup 1.0000x reference)
//
#include <hip/hip_runtime.h>
#include <cfloat>

#define NROW   256      // B*E rows
#define RLEN   65536    // N*N elements per row
#define TPB    1024
#define KPT    16       // float4 groups per thread (16*4 = 64 elems)
#define MAXC   8192     // candidate capacity (LDS); cnt ~ e^8 ~ 2500-4500 expected
#define NITER  64       // scan length (local_k)
#define KSEL   64       // top-k
#define THETA_OFF 8.0f  // initial candidate threshold: M0 - 8.0

// Zero the 64 MB output (float4 stores, coalesced). Runs before the main kernel.
__global__ void __launch_bounds__(TPB)
gumbel_zero_kernel(float4* __restrict__ out) {
    size_t i = (size_t)blockIdx.x * TPB + threadIdx.x;
    out[i] = make_float4(0.f, 0.f, 0.f, 0.f);
}

// R6 = R5 structure + R4 numerics.
// R5's failure root-cause: fixed exp anchor C=10*M0 puts the dominant element's
// exp argument at |y|~40-70 where __expf rel-err ~5e-6 (argument reduction),
// vs ~1e-7 at y~0 with per-iteration max anchoring (which jax's softmax does).
// That error hits the log(1-o) hair-trigger (1-o ~ 1e-4 => 5% shift in the
// correction) => chaotic trajectory divergence => flipped rank-64/65 selection.
// R4's per-iteration anchor passed with absmax 0.0; reproduce its arithmetic
// VERBATIM, only restructured: 16 waves do the two bandwidth passes, then
// waves 1..15 retire and wave 0 runs the scan + selection with zero barriers
// (butterfly __shfl_xor reductions; per-lane slot ownership c = lane + 64j).
__global__ void __launch_bounds__(TPB)
GumbelSampler_2482491097709_kernel(const float* __restrict__ scores,
                                   const float* __restrict__ gumbel,
                                   float* __restrict__ out)
{
    __shared__ float s_red[16];
    __shared__ float s_red2[16];
    __shared__ int   s_cnt;
    __shared__ float s_mx[NITER];     // recorded 10*max(flat_t) (for backfill)
    __shared__ float s_rcp[NITER];    // recorded 1/S_t (for backfill)
    __shared__ int   cand_idx[MAXC];
    __shared__ float cand_cur[MAXC];  // evolving flat value
    __shared__ float cand_kh[MAXC];   // accumulated khot

    const int tid  = threadIdx.x;
    const int lane = tid & 63;
    const int wid  = tid >> 6;

    // XCD swizzle: co-locate the 4 e-blocks of each b on one XCD (perf only).
    const int q    = blockIdx.x;
    const int xcd  = q & 7;
    const int slot = q >> 3;
    const int b    = xcd * 8 + (slot & 7);
    const int e    = slot >> 3;
    const int r    = b * 4 + e;

    const float*  __restrict__ srow = scores + (size_t)b * RLEN * 4 + e;
    const float4* __restrict__ g4   = (const float4*)(gumbel + (size_t)r * RLEN);

    // ---- Pass 1 (all 16 waves): block max M0 ----
    float lm = -FLT_MAX;
    for (int k = 0; k < KPT; ++k) {
        int p4 = tid + k * TPB;
        float4 g = g4[p4];
        int p = p4 * 4;
        float v0 = srow[(size_t)(p + 0) * 4] + g.x;
        float v1 = srow[(size_t)(p + 1) * 4] + g.y;
        float v2 = srow[(size_t)(p + 2) * 4] + g.z;
        float v3 = srow[(size_t)(p + 3) * 4] + g.w;
        lm = fmaxf(lm, fmaxf(fmaxf(v0, v1), fmaxf(v2, v3)));
    }
#pragma unroll
    for (int o = 32; o; o >>= 1) lm = fmaxf(lm, __shfl_xor(lm, o));
    if (lane == 0) s_red[wid] = lm;
    __syncthreads();
    float M0 = s_red[0];
#pragma unroll
    for (int w = 1; w < 16; ++w) M0 = fmaxf(M0, s_red[w]);   // uniform order
    const float C = M0 * 10.0f;          // anchor for the frozen-tail U only

    // ---- Pass 2 (all 16 waves): collect candidates >= theta; Mu/U of rest ----
    float theta = M0 - THETA_OFF;
    int cnt;
    while (true) {
        __syncthreads();                 // M0/s_red reads done; prior s_cnt reads done
        if (tid == 0) s_cnt = 0;
        __syncthreads();
        float mu = -FLT_MAX, u = 0.f;
        for (int k = 0; k < KPT; ++k) {
            int p4 = tid + k * TPB;
            float4 g = g4[p4];
            int p = p4 * 4;
            float vv[4] = { srow[(size_t)(p + 0) * 4] + g.x,
                            srow[(size_t)(p + 1) * 4] + g.y,
                            srow[(size_t)(p + 2) * 4] + g.z,
                            srow[(size_t)(p + 3) * 4] + g.w };
#pragma unroll
            for (int j = 0; j < 4; ++j) {
                float v = vv[j];
                if (v >= theta) {
                    int sl = atomicAdd(&s_cnt, 1);
                    if (sl < MAXC) {
                        cand_idx[sl] = p + j; cand_cur[sl] = v; cand_kh[sl] = 0.f;
                    }
                } else {
                    mu = fmaxf(mu, v);
                    u += __expf(fmaf(v, 10.f, -C));
                }
            }
        }
#pragma unroll
        for (int o = 32; o; o >>= 1) {
            mu = fmaxf(mu, __shfl_xor(mu, o));
            u += __shfl_xor(u, o);
        }
        if (lane == 0) { s_red[wid] = mu; s_red2[wid] = u; }
        __syncthreads();                 // cand arrays + partials visible
        cnt = s_cnt;
        if (cnt <= MAXC) break;
        theta += 1.0f;                   // overflow retry (statistically never)
    }

    if (wid != 0) return;                // waves 1..15 done; wave 0 owns the rest

    // ================== WAVE 0 ONLY — no barriers below ==================
    float Mu = (lane < 16) ? s_red[lane]  : -FLT_MAX;
    float U  = (lane < 16) ? s_red2[lane] : 0.f;
#pragma unroll
    for (int o = 32; o; o >>= 1) {
        Mu = fmaxf(Mu, __shfl_xor(Mu, o));
        U += __shfl_xor(U, o);
    }

    // ---- Scan: 64 iterations, R4-verbatim arithmetic ----
    // Iteration t, phase A (t>0): per candidate
    //   y = fmaf(cur, 10, -mx_{t-1});  o = __expf(y) * rcp_{t-1}   (= onehot_{t-1})
    //   kh += o;  if (y > t2_{t-1}) cur += __logf(fmaxf(1-o, FLT_MIN))
    //   (skip is exact: o <= e^-18.03 => fl(1-o) = 1)
    // then mx_t = 10*max(max_c cur, Mu);  phase B: S_t = sum exp(10 cur - mx_t)
    //   + exp(C - mx_t + log U);  rcp_t = 1/S_t;  t2_t = ln(S_t) - 18.03.
    bool  noexp = false;
    float pmx = 0.f, prcp = 0.f, pt2 = 0.f;   // iteration t-1's mx/rcp/t2
    for (int t = 0; t < NITER; ++t) {
        // Phase A: correction for t-1, running max of post-correction values
        float lmx = -FLT_MAX;
        if (t == 0) {
            for (int c = lane; c < cnt; c += 64) lmx = fmaxf(lmx, cand_cur[c]);
        } else {
            for (int c = lane; c < cnt; c += 64) {
                float cur = cand_cur[c];
                float y = fmaf(cur, 10.f, -pmx);
                float o = __expf(y) * prcp;
                cand_kh[c] += o;
                if (y > pt2) {
                    cur += __logf(fmaxf(1.f - o, FLT_MIN));
                    cand_cur[c] = cur;
                }
                lmx = fmaxf(lmx, cur);
            }
        }
#pragma unroll
        for (int o = 32; o; o >>= 1) lmx = fmaxf(lmx, __shfl_xor(lmx, o));
        const float mx = fmaxf(lmx, Mu) * 10.f;   // includes frozen-tail max

        // Phase B: sumexp at anchor mx (re-read post-correction values)
        float ls = 0.f;
        for (int c = lane; c < cnt; c += 64)
            ls += __expf(fmaf(cand_cur[c], 10.f, -mx));
#pragma unroll
        for (int o = 32; o; o >>= 1) ls += __shfl_xor(ls, o);
        float S = ls;
        if (U > 0.f) S += __expf(C - mx + __logf(U));  // frozen tail, log-space
        float lnse = __logf(S);
        float rcp  = 1.f / S;
        float t2   = lnse - 18.03f;
        if (lane == 0) { s_mx[t] = mx; s_rcp[t] = rcp; }  // history for backfill

        pmx = mx; prcp = rcp; pt2 = t2;

        // Expansion trigger: non-candidate onehot_t > 2^-25 requires
        // 10*Mu > Lse_t - 17.33; fire 2.67 early. Expansion lands BEFORE
        // iteration t+1 applies rcp_t corrections -> exact.
        if (!noexp && t < NITER - 1) {
            float Lse = mx + lnse;
            if (10.f * Mu > Lse - 20.f) {
                float thOld = theta;
                float thN   = (Lse - 26.f) * 0.1f;
                int   oldc  = cnt;
                float mu2 = -FLT_MAX, u2 = 0.f;
                for (int k = 0; k < KPT * 16; ++k) {   // 256 iters x 64 lanes
                    int p4 = lane + k * 64;
                    float4 g = g4[p4];
                    int p = p4 * 4;
                    float vv[4] = { srow[(size_t)(p + 0) * 4] + g.x,
                                    srow[(size_t)(p + 1) * 4] + g.y,
                                    srow[(size_t)(p + 2) * 4] + g.z,
                                    srow[(size_t)(p + 3) * 4] + g.w };
#pragma unroll
                    for (int j = 0; j < 4; ++j) {
                        float v = vv[j];
                        if (v < thOld) {
                            if (v >= thN) {
                                int sl = atomicAdd(&s_cnt, 1);
                                if (sl < MAXC) {
                                    cand_idx[sl] = p + j;
                                    cand_cur[sl] = v;     // bit-frozen so far
                                    // khot backfill for tt < t (each < e^-20):
                                    float kb = 0.f;
                                    for (int tt = 0; tt < t; ++tt)
                                        kb += __expf(fmaf(v, 10.f, -s_mx[tt]))
                                              * s_rcp[tt];
                                    cand_kh[sl] = kb;
                                }
                            } else {
                                mu2 = fmaxf(mu2, v);
                                u2 += __expf(fmaf(v, 10.f, -C));
                            }
                        }
                    }
                }
#pragma unroll
                for (int o = 32; o; o >>= 1) {
                    mu2 = fmaxf(mu2, __shfl_xor(mu2, o));
                    u2 += __shfl_xor(u2, o);
                }
                int newc = s_cnt;
                if (newc > MAXC) {
                    if (lane == 0) s_cnt = oldc;   // discard partial appends
                    noexp = true;                  // keep old Mu/U/theta
                } else {
                    cnt = newc; Mu = mu2; U = u2; theta = thN;
                }
            }
        }
    }
    // final iteration's onehot (t = NITER-1): accumulate only, no correction
    for (int c = lane; c < cnt; c += 64) {
        float y = fmaf(cand_cur[c], 10.f, -pmx);
        cand_kh[c] += __expf(y) * prcp;
    }

    // ---- Selection: 64 argmax rounds, jax top_k tie-break (val desc, idx asc).
    // Per-lane slot ownership c = lane + 64j (j < 128); claims in register
    // bitmasks -> no LDS write->read hazards, no barriers.
    unsigned long long cl0 = 0ull, cl1 = 0ull;
    float selv = -1.f; int seli = 0;
    for (int round = 0; round < KSEL; ++round) {
        float bv = -1.f; int bi = 0x7fffffff; int bj = -1; int bl = lane;
        int j = 0;
        for (int c = lane; c < cnt; c += 64, ++j) {
            bool claimed = (j < 64) ? ((cl0 >> j) & 1ull)
                                    : ((cl1 >> (j - 64)) & 1ull);
            if (claimed) continue;
            float v = cand_kh[c];
            int   i = cand_idx[c];
            if (v > bv || (v == bv && i < bi)) { bv = v; bi = i; bj = j; }
        }
#pragma unroll
        for (int o = 32; o; o >>= 1) {
            float ov = __shfl_xor(bv, o);
            int   oi = __shfl_xor(bi, o);
            int   oj = __shfl_xor(bj, o);
            int   ol = __shfl_xor(bl, o);
            if (ov > bv || (ov == bv && oi < bi)) { bv = ov; bi = oi; bj = oj; bl = ol; }
        }
        // all lanes now agree on the winner (bv, bi, bj, bl)
        if (lane == round) { selv = bv; seli = bi; }
        if (bv >= 0.f && lane == bl) {
            if (bj < 64) cl0 |= 1ull << bj; else cl1 |= 1ull << (bj - 64);
        }
    }

    // ---- Scatter: lane k writes round-k winner ----
    if (selv >= 0.f) {
        out[((size_t)b * RLEN + (size_t)seli) * 4 + e] = (1.f - selv) + selv;
    }
}

extern "C" void kernel_launch(void* const* d_in, const int* in_sizes, int n_in,
                              void* d_out, int out_size, void* d_ws, size_t ws_size,
                              hipStream_t stream) {
    const float* scores = (const float*)d_in[0];   // [B=64, N=256, N=256, E=4] f32
    const float* gumbel = (const float*)d_in[1];   // [B*E=256, N*N=65536] f32
    float* out = (float*)d_out;                    // [B, N, N, E] f32

    int nvec4 = out_size / 4;
    int zgrid = (nvec4 + TPB - 1) / TPB;
    gumbel_zero_kernel<<<zgrid, TPB, 0, stream>>>((float4*)out);
    GumbelSampler_2482491097709_kernel<<<NROW, TPB, 0, stream>>>(scores, gumbel, out);
}

// Round 7
// 620.392 us; speedup vs baseline: 4.1692x; 4.1692x over previous
//
#include <hip/hip_runtime.h>
#include <cfloat>

#define NROW   256      // B*E rows
#define RLEN   65536    // N*N elements per row
#define TPB    1024
#define KPT    16       // float4 groups per thread (16*4 = 64 elems)
#define REGS   8        // candidate slots per thread, in VGPRs
#define MAXC   (TPB*REGS)   // 8192
#define NITER  64       // scan length (local_k)
#define KSEL   64       // top-k
#define THETA_OFF 8.0f  // initial candidate threshold: M0 - 8.0

// Zero the 64 MB output (float4 stores, coalesced). Runs before the main kernel.
__global__ void __launch_bounds__(TPB)
gumbel_zero_kernel(float4* __restrict__ out) {
    size_t i = (size_t)blockIdx.x * TPB + threadIdx.x;
    out[i] = make_float4(0.f, 0.f, 0.f, 0.f);
}

// R7 = R4/R6-verbatim numerics (both passed absmax 0.0) with the parallelism
// fixed. R6's wave-0-only scan was a single-wave LDS-latency chain (~600 cyc
// per slot-visit, 2.5 ms, VALUBusy 2.8%). Here: candidates live in REGISTERS
// (thread owns slots sl = tid + 1024*j, j<8; rcur/rkh in VGPRs), all 16 waves
// run the scan, and reductions are distributed: intra-wave butterfly -> 16
// partials to LDS -> ONE barrier -> every thread reduces the 16 in a fixed
// order (bit-uniform result => uniform branching). Alternating buffers give
// 2 barriers/iter (scan) and 1 barrier/round (selection, parity-buffered).
__global__ void __launch_bounds__(TPB)
GumbelSampler_2482491097709_kernel(const float* __restrict__ scores,
                                   const float* __restrict__ gumbel,
                                   float* __restrict__ out)
{
    __shared__ float s_A[16];       // scan max partials
    __shared__ float s_B[16];       // scan sum partials
    __shared__ float s_EA[16];      // collect/expansion max partials
    __shared__ float s_EB[16];      // collect/expansion sum partials
    __shared__ float s_SV[2][16];   // selection val partials (round parity)
    __shared__ int   s_SI[2][16];   // selection idx partials
    __shared__ float s_mx[NITER];   // recorded 10*max(flat_t) (for backfill)
    __shared__ float s_rcp[NITER];  // recorded 1/S_t (for backfill)
    __shared__ int   s_cnt;
    __shared__ int   cand_idx[MAXC];
    __shared__ float cand_cur[MAXC]; // staging only; live values sit in VGPRs

    const int tid  = threadIdx.x;
    const int lane = tid & 63;
    const int wid  = tid >> 6;

    // XCD swizzle: co-locate the 4 e-blocks of each b on one XCD (perf only).
    const int q    = blockIdx.x;
    const int xcd  = q & 7;
    const int slot = q >> 3;
    const int b    = xcd * 8 + (slot & 7);
    const int e    = slot >> 3;
    const int r    = b * 4 + e;

    const float*  __restrict__ srow = scores + (size_t)b * RLEN * 4 + e;
    const float4* __restrict__ g4   = (const float4*)(gumbel + (size_t)r * RLEN);

    // ---- Pass 1 (all 16 waves): block max M0 ----
    float lm = -FLT_MAX;
    for (int k = 0; k < KPT; ++k) {
        int p4 = tid + k * TPB;
        float4 g = g4[p4];
        int p = p4 * 4;
        float v0 = srow[(size_t)(p + 0) * 4] + g.x;
        float v1 = srow[(size_t)(p + 1) * 4] + g.y;
        float v2 = srow[(size_t)(p + 2) * 4] + g.z;
        float v3 = srow[(size_t)(p + 3) * 4] + g.w;
        lm = fmaxf(lm, fmaxf(fmaxf(v0, v1), fmaxf(v2, v3)));
    }
#pragma unroll
    for (int o = 32; o; o >>= 1) lm = fmaxf(lm, __shfl_xor(lm, o));
    if (lane == 0) s_A[wid] = lm;
    __syncthreads();
    float M0 = s_A[0];
#pragma unroll
    for (int w = 1; w < 16; ++w) M0 = fmaxf(M0, s_A[w]);   // uniform (exact max)
    const float C = M0 * 10.0f;          // anchor for the frozen-tail U only

    // ---- Pass 2 (all 16 waves): collect candidates >= theta; Mu/U of rest ----
    float theta = M0 - THETA_OFF;
    int cnt;
    while (true) {
        __syncthreads();                 // prior s_cnt / s_A reads done
        if (tid == 0) s_cnt = 0;
        __syncthreads();
        float mu = -FLT_MAX, u = 0.f;
        for (int k = 0; k < KPT; ++k) {
            int p4 = tid + k * TPB;
            float4 g = g4[p4];
            int p = p4 * 4;
            float vv[4] = { srow[(size_t)(p + 0) * 4] + g.x,
                            srow[(size_t)(p + 1) * 4] + g.y,
                            srow[(size_t)(p + 2) * 4] + g.z,
                            srow[(size_t)(p + 3) * 4] + g.w };
#pragma unroll
            for (int j = 0; j < 4; ++j) {
                float v = vv[j];
                if (v >= theta) {
                    int sl = atomicAdd(&s_cnt, 1);
                    if (sl < MAXC) { cand_idx[sl] = p + j; cand_cur[sl] = v; }
                } else {
                    mu = fmaxf(mu, v);
                    u += __expf(fmaf(v, 10.f, -C));
                }
            }
        }
#pragma unroll
        for (int o = 32; o; o >>= 1) {
            mu = fmaxf(mu, __shfl_xor(mu, o));
            u += __shfl_xor(u, o);
        }
        if (lane == 0) { s_EA[wid] = mu; s_EB[wid] = u; }
        __syncthreads();                 // staging + partials visible
        cnt = s_cnt;
        if (cnt <= MAXC) break;
        theta += 1.0f;                   // overflow retry (statistically never)
    }
    float Mu = -FLT_MAX, U = 0.f;
#pragma unroll
    for (int w = 0; w < 16; ++w) { Mu = fmaxf(Mu, s_EA[w]); U += s_EB[w]; }

    // ---- Redistribute: each thread pulls its owned slots into VGPRs ----
    float rcur[REGS], rkh[REGS];
#pragma unroll
    for (int j = 0; j < REGS; ++j) {
        int sl = tid + TPB * j;
        rcur[j] = (sl < cnt) ? cand_cur[sl] : 0.f;
        rkh[j]  = 0.f;
    }

    // ---- Scan: 64 iterations, R4-verbatim per-element arithmetic ----
    bool  noexp = false;
    float pmx = 0.f, prcp = 0.f, pt2 = 0.f;
    for (int t = 0; t < NITER; ++t) {
        // Phase A: apply iteration t-1's onehot (kh += o) + correction, run max
        float lmx = -FLT_MAX;
        if (t == 0) {
#pragma unroll
            for (int j = 0; j < REGS; ++j)
                if (tid + TPB * j < cnt) lmx = fmaxf(lmx, rcur[j]);
        } else {
#pragma unroll
            for (int j = 0; j < REGS; ++j) {
                if (tid + TPB * j < cnt) {
                    float cur = rcur[j];
                    float y = fmaf(cur, 10.f, -pmx);
                    float o = __expf(y) * prcp;
                    rkh[j] += o;
                    if (y > pt2) {       // o <= e^-18.03 => fl(1-o)=1, skip exact
                        cur += __logf(fmaxf(1.f - o, FLT_MIN));
                        rcur[j] = cur;
                    }
                    lmx = fmaxf(lmx, cur);
                }
            }
        }
#pragma unroll
        for (int o = 32; o; o >>= 1) lmx = fmaxf(lmx, __shfl_xor(lmx, o));
        if (lane == 0) s_A[wid] = lmx;
        __syncthreads();
        float gm = s_A[0];
#pragma unroll
        for (int w = 1; w < 16; ++w) gm = fmaxf(gm, s_A[w]);   // uniform
        const float mx = fmaxf(gm, Mu) * 10.f;   // includes frozen-tail max

        // Phase B: sumexp at anchor mx
        float ls = 0.f;
#pragma unroll
        for (int j = 0; j < REGS; ++j)
            if (tid + TPB * j < cnt) ls += __expf(fmaf(rcur[j], 10.f, -mx));
#pragma unroll
        for (int o = 32; o; o >>= 1) ls += __shfl_xor(ls, o);
        if (lane == 0) s_B[wid] = ls;
        __syncthreads();
        float S = 0.f;
#pragma unroll
        for (int w = 0; w < 16; ++w) S += s_B[w];              // uniform order
        if (U > 0.f) S += __expf(C - mx + __logf(U));  // frozen tail, log-space
        float lnse = __logf(S);
        float rcp  = 1.f / S;
        float t2   = lnse - 18.03f;
        if (tid == 0) { s_mx[t] = mx; s_rcp[t] = rcp; }  // history for backfill
        pmx = mx; prcp = rcp; pt2 = t2;

        // Expansion trigger (uniform): non-candidate onehot_t > 2^-25 requires
        // 10*Mu > Lse_t - 17.33; fire 2.67 early. Lands before iteration t+1
        // applies rcp_t corrections -> exact.
        if (!noexp && t < NITER - 1) {
            float Lse = mx + lnse;
            if (10.f * Mu > Lse - 20.f) {
                float thOld = theta;
                float thN   = (Lse - 26.f) * 0.1f;
                int   oldc  = cnt;
                float mu2 = -FLT_MAX, u2 = 0.f;
                for (int k = 0; k < KPT; ++k) {
                    int p4 = tid + k * TPB;
                    float4 g = g4[p4];
                    int p = p4 * 4;
                    float vv[4] = { srow[(size_t)(p + 0) * 4] + g.x,
                                    srow[(size_t)(p + 1) * 4] + g.y,
                                    srow[(size_t)(p + 2) * 4] + g.z,
                                    srow[(size_t)(p + 3) * 4] + g.w };
#pragma unroll
                    for (int j = 0; j < 4; ++j) {
                        float v = vv[j];
                        if (v < thOld) {
                            if (v >= thN) {
                                int sl = atomicAdd(&s_cnt, 1);
                                if (sl < MAXC) {
                                    cand_idx[sl] = p + j;
                                    cand_cur[sl] = v;     // bit-frozen so far
                                }
                            } else {
                                mu2 = fmaxf(mu2, v);
                                u2 += __expf(fmaf(v, 10.f, -C));
                            }
                        }
                    }
                }
#pragma unroll
                for (int o = 32; o; o >>= 1) {
                    mu2 = fmaxf(mu2, __shfl_xor(mu2, o));
                    u2 += __shfl_xor(u2, o);
                }
                if (lane == 0) { s_EA[wid] = mu2; s_EB[wid] = u2; }
                __syncthreads();         // appends + partials visible
                int newc = s_cnt;
                if (newc > MAXC) {
                    if (tid == 0) s_cnt = oldc;  // discard partial appends
                    noexp = true;                // uniform; s_cnt never read again
                } else {
                    float m2 = -FLT_MAX, uu = 0.f;
#pragma unroll
                    for (int w = 0; w < 16; ++w) {
                        m2 = fmaxf(m2, s_EA[w]); uu += s_EB[w];
                    }
                    Mu = m2; U = uu; theta = thN;
                    // owners pull their newly-appended slots + khot backfill
#pragma unroll
                    for (int j = 0; j < REGS; ++j) {
                        int sl = tid + TPB * j;
                        if (sl >= oldc && sl < newc) {
                            float v = cand_cur[sl];
                            rcur[j] = v;
                            float kb = 0.f;   // onehots tt<t (each < e^-20)
                            for (int tt = 0; tt < t; ++tt)
                                kb += __expf(fmaf(v, 10.f, -s_mx[tt])) * s_rcp[tt];
                            rkh[j] = kb;
                        }
                    }
                    cnt = newc;
                }
            }
        }
    }
    // final iteration's onehot (t = NITER-1): accumulate only, no correction
#pragma unroll
    for (int j = 0; j < REGS; ++j) {
        if (tid + TPB * j < cnt) {
            float y = fmaf(rcur[j], 10.f, -pmx);
            rkh[j] += __expf(y) * prcp;
        }
    }

    // cache indices into regs (static after last expansion; barriers since)
    int ridx[REGS];
#pragma unroll
    for (int j = 0; j < REGS; ++j) {
        int sl = tid + TPB * j;
        ridx[j] = (sl < cnt) ? cand_idx[sl] : 0x7fffffff;
    }

    // ---- Selection: 64 argmax rounds, jax top_k tie-break (val desc, idx asc).
    // 1 barrier/round via parity-buffered partials; claims in per-thread masks.
    unsigned cl = 0;                  // claimed bitmask over REGS slots
    float selv = -1.f; int seli = 0;
    for (int round = 0; round < KSEL; ++round) {
        const int par = round & 1;
        float bv = -1.f; int bi = 0x7fffffff;
#pragma unroll
        for (int j = 0; j < REGS; ++j) {
            int sl = tid + TPB * j;
            if (sl < cnt && !((cl >> j) & 1u)) {
                float v = rkh[j]; int i = ridx[j];
                if (v > bv || (v == bv && i < bi)) { bv = v; bi = i; }
            }
        }
#pragma unroll
        for (int o = 32; o; o >>= 1) {
            float ov = __shfl_xor(bv, o);
            int   oi = __shfl_xor(bi, o);
            if (ov > bv || (ov == bv && oi < bi)) { bv = ov; bi = oi; }
        }
        if (lane == 0) { s_SV[par][wid] = bv; s_SI[par][wid] = bi; }
        __syncthreads();
        float Bv = s_SV[par][0]; int Bi = s_SI[par][0];
#pragma unroll
        for (int w = 1; w < 16; ++w) {
            float v = s_SV[par][w]; int i = s_SI[par][w];
            if (v > Bv || (v == Bv && i < Bi)) { Bv = v; Bi = i; }
        }
        if (tid == round) { selv = Bv; seli = Bi; }
        if (Bv >= 0.f) {              // owner claims (idx unique => one claimer)
#pragma unroll
            for (int j = 0; j < REGS; ++j) {
                int sl = tid + TPB * j;
                if (sl < cnt && !((cl >> j) & 1u) &&
                    rkh[j] == Bv && ridx[j] == Bi) cl |= 1u << j;
            }
        }
    }

    // ---- Scatter: thread k writes round-k winner; out pre-zeroed ----
    if (tid < KSEL && selv >= 0.f) {
        out[((size_t)b * RLEN + (size_t)seli) * 4 + e] = (1.f - selv) + selv;
    }
}

extern "C" void kernel_launch(void* const* d_in, const int* in_sizes, int n_in,
                              void* d_out, int out_size, void* d_ws, size_t ws_size,
                              hipStream_t stream) {
    const float* scores = (const float*)d_in[0];   // [B=64, N=256, N=256, E=4] f32
    const float* gumbel = (const float*)d_in[1];   // [B*E=256, N*N=65536] f32
    float* out = (float*)d_out;                    // [B, N, N, E] f32

    int nvec4 = out_size / 4;
    int zgrid = (nvec4 + TPB - 1) / TPB;
    gumbel_zero_kernel<<<zgrid, TPB, 0, stream>>>((float4*)out);
    GumbelSampler_2482491097709_kernel<<<NROW, TPB, 0, stream>>>(scores, gumbel, out);
}